// Round 2
// baseline (112.367 us; speedup 1.0000x reference)
//
#include <hip/hip_runtime.h>
#include <hip/hip_bf16.h>

// Elementwise: theta = in + w;  c = cos(theta);  out = {c0, c0*c1} per row.
// Rows are (BATCH, 2) fp32, so one float4 = two complete rows. Memory-bound:
// 64 MiB read + 64 MiB write. Grid-stride, 2048 blocks x 256 threads.

__global__ __launch_bounds__(256) void quantum_layer_kernel(
    const float* __restrict__ in,     // BATCH*2 floats
    const float* __restrict__ w,      // 2 floats
    float* __restrict__ out,          // BATCH*2 floats
    int n4)                           // number of float4 chunks = BATCH*2/4
{
    const float w0 = w[0];
    const float w1 = w[1];

    const float4* __restrict__ in4 = reinterpret_cast<const float4*>(in);
    float4* __restrict__ out4 = reinterpret_cast<float4*>(out);

    int stride = gridDim.x * blockDim.x;
    for (int i = blockIdx.x * blockDim.x + threadIdx.x; i < n4; i += stride) {
        float4 v = in4[i];
        // v = {row_a.q0, row_a.q1, row_b.q0, row_b.q1}
        float c0a = cosf(v.x + w0);
        float c1a = cosf(v.y + w1);
        float c0b = cosf(v.z + w0);
        float c1b = cosf(v.w + w1);
        float4 r;
        r.x = c0a;
        r.y = c0a * c1a;
        r.z = c0b;
        r.w = c0b * c1b;
        out4[i] = r;
    }
}

extern "C" void kernel_launch(void* const* d_in, const int* in_sizes, int n_in,
                              void* d_out, int out_size, void* d_ws, size_t ws_size,
                              hipStream_t stream) {
    const float* in = (const float*)d_in[0];
    const float* w  = (const float*)d_in[1];
    float* out      = (float*)d_out;

    int n_elems = in_sizes[0];       // BATCH * 2
    int n4 = n_elems / 4;            // BATCH*2 divisible by 4 (BATCH = 8M)

    const int block = 256;
    int grid = (n4 + block - 1) / block;
    if (grid > 2048) grid = 2048;

    quantum_layer_kernel<<<grid, block, 0, stream>>>(in, w, out, n4);
}